// Round 4
// baseline (332.657 us; speedup 1.0000x reference)
//
#include <hip/hip_runtime.h>
#include <hip/hip_bf16.h>
#include <stdint.h>

// SingleHeadAttention: B=8 T=2048 E=1024 A=1024, fp32 in/out, bf16 MFMA inside.
// Round 4: revert to the verified R1 128x128/BK=64/2-barrier GEMM bodies
// (m97 structure, 32KB LDS -> 4-5 blocks/CU so cross-block overlap hides the
// barrier/vmcnt stalls), and fix ONLY grid shape + XCD mapping:
//   qkv:   3072 blocks, XCD owns m-band; hot set X-band 2MB + W-slice 2MB (L2)
//   score: compact lower-triangle grid (1088 blocks), XCD = batch
//   pv:    1024 blocks, XCD = batch, mt descending (long-K first)

#define BB 8
#define TT 2048
#define EE 1024
#define AA 1024
#define MM (BB * TT)  // 16384

typedef short bf16x8 __attribute__((ext_vector_type(8)));
typedef float f32x4 __attribute__((ext_vector_type(4)));

#define GLOAD_LDS16(g, l)                                                      \
  __builtin_amdgcn_global_load_lds(                                            \
      (const __attribute__((address_space(1))) void*)(g),                      \
      (__attribute__((address_space(3))) void*)(l), 16, 0, 0)

// Stage a 128-row x 64-col bf16 tile (row-major, row stride `stride` elems)
// into linear LDS [128][64]. 256 threads, 16B per thread per round, 4 rounds.
__device__ __forceinline__ void stage_tile(const short* __restrict__ g,
                                           size_t stride, short* lds, int tid) {
#pragma unroll
  for (int r = 0; r < 4; ++r) {
    int t = r * 256 + tid;
    int row = t >> 3;          // 8 x 16B chunks per 128B row
    int c = (t & 7) * 8;       // col offset in shorts
    GLOAD_LDS16(g + (size_t)row * stride + c, lds + (size_t)t * 8);
  }
}

// One BK=64 step of MFMA on staged tiles. acc[4][4] per wave (64x64 subtile).
__device__ __forceinline__ void mfma_step(const short* As, const short* Bs,
                                          f32x4 acc[4][4], int lane, int wr,
                                          int wc) {
  int lrow = lane & 15;
  int lk = (lane >> 4) * 8;
#pragma unroll
  for (int kk = 0; kk < 64; kk += 32) {
    bf16x8 a[4], b[4];
#pragma unroll
    for (int i = 0; i < 4; ++i)
      a[i] = *(const bf16x8*)&As[(wr * 64 + i * 16 + lrow) * 64 + kk + lk];
#pragma unroll
    for (int j = 0; j < 4; ++j)
      b[j] = *(const bf16x8*)&Bs[(wc * 64 + j * 16 + lrow) * 64 + kk + lk];
#pragma unroll
    for (int i = 0; i < 4; ++i)
#pragma unroll
      for (int j = 0; j < 4; ++j)
        acc[i][j] =
            __builtin_amdgcn_mfma_f32_16x16x32_bf16(a[i], b[j], acc[i][j], 0, 0, 0);
  }
}

__global__ void cvt_bf16(const float* __restrict__ src, short* __restrict__ dst,
                         int n4) {
  int stride = gridDim.x * blockDim.x;
  for (int i = blockIdx.x * blockDim.x + threadIdx.x; i < n4; i += stride) {
    float4 v = ((const float4*)src)[i];
    __hip_bfloat16 h0 = __float2bfloat16(v.x);
    __hip_bfloat16 h1 = __float2bfloat16(v.y);
    __hip_bfloat16 h2 = __float2bfloat16(v.z);
    __hip_bfloat16 h3 = __float2bfloat16(v.w);
    short4 o;
    o.x = *(short*)&h0;
    o.y = *(short*)&h1;
    o.z = *(short*)&h2;
    o.w = *(short*)&h3;
    ((short4*)dst)[i] = o;
  }
}

// All three weights in one launch. dst = [Wq|Wk|Wv] bf16.
__global__ void cvt_w3(const float* __restrict__ wq, const float* __restrict__ wk,
                       const float* __restrict__ wv, short* __restrict__ dst) {
  const int n4 = AA * EE / 4;
  int stride = gridDim.x * blockDim.x;
  for (int i = blockIdx.x * blockDim.x + threadIdx.x; i < 3 * n4; i += stride) {
    const float* src = (i < n4) ? wq : (i < 2 * n4 ? wk : wv);
    int ii = (i < n4) ? i : (i < 2 * n4 ? i - n4 : i - 2 * n4);
    float4 v = ((const float4*)src)[ii];
    __hip_bfloat16 h0 = __float2bfloat16(v.x);
    __hip_bfloat16 h1 = __float2bfloat16(v.y);
    __hip_bfloat16 h2 = __float2bfloat16(v.z);
    __hip_bfloat16 h3 = __float2bfloat16(v.w);
    short4 o;
    o.x = *(short*)&h0;
    o.y = *(short*)&h1;
    o.z = *(short*)&h2;
    o.w = *(short*)&h3;
    ((short4*)dst)[i] = o;
  }
}

// ---------------------------------------------------------------------------
// Fused QKV: C[m, z*1024+n] = sum_k X[m,k] W[z][n,k]. grid 3072, 256 thr.
// XCD x owns m-tiles [x*16, x*16+16): j = bid>>3 in [0,384):
//   half = j/192 (m-subband of 8), z = (j%192)/64, jm = (j%64)>>3, nt = j&7.
// Hot set per XCD: X-band 8x128x1024x2 = 2MB + W z-slice 2MB -> L2-resident.
// ---------------------------------------------------------------------------
__global__ __launch_bounds__(256) void qkv_gemm(const short* __restrict__ xb,
                                                const short* __restrict__ Wb,
                                                short* __restrict__ out) {
  __shared__ __align__(16) short As[128 * 64];
  __shared__ __align__(16) short Bs[128 * 64];
  int f = blockIdx.x;
  int xcd = f & 7, j = f >> 3;     // j in [0,384)
  int half = j / 192;              // 0..1
  int j2 = j - half * 192;
  int z = j2 >> 6;                 // 0..2
  int j3 = j2 & 63;
  int mt = xcd * 16 + half * 8 + (j3 >> 3);  // 0..127
  int nt = j3 & 7;                 // 0..7

  int tid = threadIdx.x;
  int lane = tid & 63, wid = tid >> 6, wr = wid >> 1, wc = wid & 1;
  int m0 = mt * 128, n0 = nt * 128;
  const short* W = Wb + (size_t)z * AA * EE;
  short* o = out + (size_t)z * MM * AA;
  f32x4 acc[4][4];
#pragma unroll
  for (int i = 0; i < 4; ++i)
#pragma unroll
    for (int jj = 0; jj < 4; ++jj) acc[i][jj] = (f32x4){0.f, 0.f, 0.f, 0.f};

  for (int k0 = 0; k0 < EE; k0 += 64) {
    stage_tile(xb + (size_t)m0 * EE + k0, EE, As, tid);
    stage_tile(W + (size_t)n0 * EE + k0, EE, Bs, tid);
    __syncthreads();
    mfma_step(As, Bs, acc, lane, wr, wc);
    __syncthreads();
  }
  int lrow = lane & 15, lk4 = (lane >> 4) * 4;
#pragma unroll
  for (int i = 0; i < 4; ++i) {
    int row = m0 + wr * 64 + i * 16 + lk4;
#pragma unroll
    for (int jj = 0; jj < 4; ++jj) {
      int col = n0 + wc * 64 + jj * 16 + lrow;
#pragma unroll
      for (int r = 0; r < 4; ++r) {
        __hip_bfloat16 h = __float2bfloat16(acc[i][jj][r]);
        o[(size_t)(row + r) * AA + col] = *(short*)&h;
      }
    }
  }
}

// Vt[b][d][t] = Vb[b*T+t][d]. 64x64 tiles. grid (32, 16, 8).
__global__ __launch_bounds__(256) void transpose_v(const short* __restrict__ Vb,
                                                   short* __restrict__ Vt) {
  __shared__ __align__(16) short lds[64 * 72];
  int t0 = blockIdx.x * 64;
  int d0 = blockIdx.y * 64;
  int b = blockIdx.z;
  int tid = threadIdx.x;
  const short* src = Vb + ((size_t)b * TT + t0) * AA + d0;
#pragma unroll
  for (int r = 0; r < 2; ++r) {
    int t = r * 256 + tid;
    int row = t >> 3;
    int c = (t & 7) * 8;
    *(bf16x8*)&lds[row * 72 + c] = *(const bf16x8*)&src[(size_t)row * AA + c];
  }
  __syncthreads();
  short* dst = Vt + ((size_t)b * AA + d0) * TT + t0;
#pragma unroll
  for (int r = 0; r < 2; ++r) {
    int t = r * 256 + tid;
    int d = t >> 3;
    int c = (t & 7) * 8;
    bf16x8 w;
#pragma unroll
    for (int e = 0; e < 8; ++e) w[e] = lds[(c + e) * 72 + d];
    *(bf16x8*)&dst[(size_t)d * TT + c] = w;
  }
}

// ---------------------------------------------------------------------------
// Scores: Pu[b][q][k] = exp(scale*Q.K)|k<=q (bf16 unnormalized); rowsum atomics.
// Compact lower-triangle grid: 1088 blocks (8 b x 136 tri), XCD = batch.
// ---------------------------------------------------------------------------
__global__ __launch_bounds__(256) void score_gemm(const short* __restrict__ Qb,
                                                  const short* __restrict__ Kb,
                                                  short* __restrict__ Pu,
                                                  float* __restrict__ lsum) {
  int f = blockIdx.x;
  int b = f & 7;
  int j = f >> 3;  // tri index in [0,136)
  int mt = 0;
  while ((mt + 1) * (mt + 2) / 2 <= j) ++mt;
  int nt = j - mt * (mt + 1) / 2;
  int q0 = mt * 128, c0 = nt * 128;

  __shared__ __align__(16) short As[128 * 64];
  __shared__ __align__(16) short Bs[128 * 64];
  int tid = threadIdx.x;
  int lane = tid & 63, wid = tid >> 6, wr = wid >> 1, wc = wid & 1;
  const short* Q = Qb + (size_t)b * TT * AA;
  const short* K = Kb + (size_t)b * TT * AA;
  f32x4 acc[4][4];
#pragma unroll
  for (int i = 0; i < 4; ++i)
#pragma unroll
    for (int jj = 0; jj < 4; ++jj) acc[i][jj] = (f32x4){0.f, 0.f, 0.f, 0.f};

  for (int k0 = 0; k0 < AA; k0 += 64) {
    stage_tile(Q + (size_t)q0 * AA + k0, AA, As, tid);
    stage_tile(K + (size_t)c0 * AA + k0, AA, Bs, tid);
    __syncthreads();
    mfma_step(As, Bs, acc, lane, wr, wc);
    __syncthreads();
  }
  const float scale = 0.03125f;  // 1/sqrt(1024)
  short* P = Pu + (size_t)b * TT * TT;
  int lrow = lane & 15, lk4 = (lane >> 4) * 4;
#pragma unroll
  for (int i = 0; i < 4; ++i) {
#pragma unroll
    for (int r = 0; r < 4; ++r) {
      int q = q0 + wr * 64 + i * 16 + lk4 + r;
      float rs = 0.f;
#pragma unroll
      for (int jj = 0; jj < 4; ++jj) {
        int kx = c0 + wc * 64 + jj * 16 + lrow;
        float e = (kx <= q) ? __expf(acc[i][jj][r] * scale) : 0.f;
        rs += e;
        __hip_bfloat16 h = __float2bfloat16(e);
        P[(size_t)q * TT + kx] = *(short*)&h;
      }
      rs += __shfl_xor(rs, 1);
      rs += __shfl_xor(rs, 2);
      rs += __shfl_xor(rs, 4);
      rs += __shfl_xor(rs, 8);
      if (lrow == 0) atomicAdd(&lsum[b * TT + q], rs);
    }
  }
}

// ---------------------------------------------------------------------------
// PV: out[b][q][d] = (sum_{k<=diag} Pu[q,k] * Vt[d,k]) / lsum[q].
// grid 1024 (8 b x 16 mt x 8 nt), XCD = batch, mt DESCENDING (long-K first).
// ---------------------------------------------------------------------------
__global__ __launch_bounds__(256) void pv_gemm(const short* __restrict__ Pu,
                                               const short* __restrict__ Vt,
                                               const float* __restrict__ lsum,
                                               float* __restrict__ out) {
  int f = blockIdx.x;
  int b = f & 7;
  int j = f >> 3;             // [0,128)
  int mt = 15 - (j >> 3);     // descending: K-heavy blocks dispatch first
  int nt = j & 7;
  int q0 = mt * 128, n0 = nt * 128;

  __shared__ __align__(16) short As[128 * 64];
  __shared__ __align__(16) short Bs[128 * 64];
  int tid = threadIdx.x;
  int lane = tid & 63, wid = tid >> 6, wr = wid >> 1, wc = wid & 1;
  const short* P = Pu + (size_t)b * TT * TT;
  const short* V = Vt + (size_t)b * AA * TT;
  f32x4 acc[4][4];
#pragma unroll
  for (int i = 0; i < 4; ++i)
#pragma unroll
    for (int jj = 0; jj < 4; ++jj) acc[i][jj] = (f32x4){0.f, 0.f, 0.f, 0.f};

  int kend = q0 + 128;
  for (int k0 = 0; k0 < kend; k0 += 64) {
    stage_tile(P + (size_t)q0 * TT + k0, TT, As, tid);
    stage_tile(V + (size_t)n0 * TT + k0, TT, Bs, tid);
    __syncthreads();
    mfma_step(As, Bs, acc, lane, wr, wc);
    __syncthreads();
  }
  int lrow = lane & 15, lk4 = (lane >> 4) * 4;
#pragma unroll
  for (int i = 0; i < 4; ++i) {
#pragma unroll
    for (int r = 0; r < 4; ++r) {
      int q = q0 + wr * 64 + i * 16 + lk4 + r;
      float linv = 1.0f / lsum[b * TT + q];
#pragma unroll
      for (int jj = 0; jj < 4; ++jj) {
        int d = n0 + wc * 64 + jj * 16 + lrow;
        out[((size_t)(b * TT + q)) * AA + d] = acc[i][jj][r] * linv;
      }
    }
  }
}

extern "C" void kernel_launch(void* const* d_in, const int* in_sizes, int n_in,
                              void* d_out, int out_size, void* d_ws,
                              size_t ws_size, hipStream_t stream) {
  const float* x = (const float*)d_in[0];
  const float* Wq = (const float*)d_in[1];
  const float* Wk = (const float*)d_in[2];
  const float* Wv = (const float*)d_in[3];

  char* ws = (char*)d_ws;
  size_t oWb = 0;
  size_t oQb = oWb + (size_t)3 * AA * EE * 2;   // 6 MB weights
  size_t oKb = oQb + (size_t)MM * AA * 2;
  size_t oVb = oKb + (size_t)MM * AA * 2;
  size_t oVt = oVb + (size_t)MM * AA * 2;
  size_t oLs = oVt + (size_t)MM * AA * 2;
  size_t oXb = oLs + (size_t)MM * 4;
  size_t oPu = oXb;  // Pu (67MB) overlaps Xb (33MB): Xb dead after qkv

  short* Wb = (short*)(ws + oWb);
  short* Qb = (short*)(ws + oQb);
  short* Kb = (short*)(ws + oKb);
  short* Vb = (short*)(ws + oVb);
  short* Vt = (short*)(ws + oVt);
  float* Ls = (float*)(ws + oLs);
  short* Xb = (short*)(ws + oXb);
  short* Pu = (short*)(ws + oPu);

  cvt_bf16<<<2048, 256, 0, stream>>>(x, Xb, MM * EE / 4);
  cvt_w3<<<768, 256, 0, stream>>>(Wq, Wk, Wv, Wb);
  hipMemsetAsync(Ls, 0, (size_t)MM * 4, stream);

  qkv_gemm<<<3072, 256, 0, stream>>>(Xb, Wb, Qb);
  transpose_v<<<dim3(32, 16, 8), 256, 0, stream>>>(Vb, Vt);
  score_gemm<<<1088, 256, 0, stream>>>(Qb, Kb, Pu, Ls);
  pv_gemm<<<1024, 256, 0, stream>>>(Pu, Vt, Ls, (float*)d_out);
}

// Round 5
// 293.738 us; speedup vs baseline: 1.1325x; 1.1325x over previous
//
#include <hip/hip_runtime.h>
#include <hip/hip_bf16.h>
#include <stdint.h>

// SingleHeadAttention: B=8 T=2048 E=1024 A=1024, fp32 in/out, bf16 MFMA inside.
// Round 5 = best-of assembly:
//   qkv:   R2's 256x256 4-phase core verbatim (measured 131 us / 787 TF)
//   score: R4's compact lower-triangle 128x128 grid (1088 blocks)
//   pv:    NEW balanced pairing - block does q-strips p and 15-p (17 K-subtiles
//          each block, uniform), 512 blocks = 2/CU, XCD = batch
//   cvt_w3 single launch; transpose_v unchanged.

#define BB 8
#define TT 2048
#define EE 1024
#define AA 1024
#define MM (BB * TT)  // 16384

typedef short bf16x8 __attribute__((ext_vector_type(8)));
typedef float f32x4 __attribute__((ext_vector_type(4)));

#define GLOAD_LDS16(g, l)                                                      \
  __builtin_amdgcn_global_load_lds(                                            \
      (const __attribute__((address_space(1))) void*)(g),                      \
      (__attribute__((address_space(3))) void*)(l), 16, 0, 0)

#define SBAR()                               \
  do {                                       \
    __builtin_amdgcn_sched_barrier(0);       \
    __builtin_amdgcn_s_barrier();            \
    __builtin_amdgcn_sched_barrier(0);       \
  } while (0)

#define LGKM0()                                          \
  do {                                                   \
    asm volatile("s_waitcnt lgkmcnt(0)" ::: "memory");   \
    __builtin_amdgcn_sched_barrier(0);                   \
  } while (0)

#define VMCNT(n)                                              \
  do {                                                        \
    asm volatile("s_waitcnt vmcnt(" #n ")" ::: "memory");     \
    __builtin_amdgcn_sched_barrier(0);                        \
  } while (0)

// ---------------------------------------------------------------------------
// R2's 256x256x(K) bt-GEMM core (measured in qkv at 787 TF). 512 thr = 8 waves
// (2M x 4N), BK=64. LDS/operand: [2 buf][2 ksub][256 row][32 kc] shorts,
// st_16x32 swizzle. Staging: gload_lds w16, linear dest, pre-swizzled source.
// ---------------------------------------------------------------------------
__device__ __forceinline__ void gemm256_core(
    const short* __restrict__ gA, int lda, int a0row,
    const short* __restrict__ gB, int ldb, int b0row, int NT, short* As,
    short* Bs, f32x4 (*acc)[4]) {
  const int tid = threadIdx.x;
  const int lane = tid & 63;
  const int w = tid >> 6;
  const int wr = w >> 2, wc = w & 3;
  const int lrow = lane & 15;
  const int lk8 = (lane >> 4) * 8;
  const int swz = ((lrow >> 3) & 1) << 4;
  const int baseA = (((wr * 128 + lrow) * 32) + lk8) ^ swz;
  const int baseB = (((wc * 64 + lrow) * 32) + lk8) ^ swz;

  const short* pA[2];
  const short* pB[2];
#pragma unroll
  for (int i = 0; i < 2; ++i) {
    int chunk = 2 * w + i;
    int P = chunk * 1024 + lane * 16;           // phys byte in 16KB region
    int L = P ^ (((P >> 9) & 1) << 5);          // logical byte
    int row = L >> 6;
    int kb2 = (L & 63) >> 1;                    // shorts
    pA[i] = gA + (size_t)(a0row + row) * lda + kb2;
    pB[i] = gB + (size_t)(b0row + row) * ldb + kb2;
  }

  // Prologue: stage tiles 0,1 fully (16 loads/thread), wait tile0 (vmcnt 8).
#pragma unroll
  for (int tl = 0; tl < 2; ++tl) {
    short* Ac = As + tl * 16384;
    short* Bc = Bs + tl * 16384;
#pragma unroll
    for (int s = 0; s < 2; ++s) {
      int off = tl * 64 + s * 32;
      GLOAD_LDS16(pA[0] + off, Ac + s * 8192 + (2 * w) * 512 + lane * 8);
      GLOAD_LDS16(pA[1] + off, Ac + s * 8192 + (2 * w + 1) * 512 + lane * 8);
      GLOAD_LDS16(pB[0] + off, Bc + s * 8192 + (2 * w) * 512 + lane * 8);
      GLOAD_LDS16(pB[1] + off, Bc + s * 8192 + (2 * w + 1) * 512 + lane * 8);
    }
  }
  VMCNT(8);
  SBAR();

  for (int t = 0; t < NT; ++t) {
    short* Ac = As + (t & 1) * 16384;
    short* Bc = Bs + (t & 1) * 16384;
    const bool stg = (t < NT - 2);
    const int off2 = (t + 2) * 64;
    bf16x8 a0[4], a1[4], a2[4], a3[4], b0[4], b1[4];

    // ---- phase 0: read A m0-3/kk0 + B kk0; MFMA (mh0,kk0)
#pragma unroll
    for (int m = 0; m < 4; ++m) a0[m] = *(const bf16x8*)&Ac[baseA + m * 512];
#pragma unroll
    for (int n = 0; n < 4; ++n) b0[n] = *(const bf16x8*)&Bc[baseB + n * 512];
    SBAR();
    LGKM0();
    __builtin_amdgcn_s_setprio(1);
#pragma unroll
    for (int m = 0; m < 4; ++m)
#pragma unroll
      for (int n = 0; n < 4; ++n)
        acc[m][n] = __builtin_amdgcn_mfma_f32_16x16x32_bf16(a0[m], b0[n],
                                                            acc[m][n], 0, 0, 0);
    __builtin_amdgcn_s_setprio(0);
    SBAR();

    // ---- phase 1: read A m4-7/kk0 + A m0-3/kk1; stage B ksub0 (t+2)
#pragma unroll
    for (int m = 0; m < 4; ++m)
      a1[m] = *(const bf16x8*)&Ac[baseA + (m + 4) * 512];
#pragma unroll
    for (int m = 0; m < 4; ++m)
      a2[m] = *(const bf16x8*)&Ac[8192 + baseA + m * 512];
    if (stg) {
      GLOAD_LDS16(pB[0] + off2, Bc + (2 * w) * 512 + lane * 8);
      GLOAD_LDS16(pB[1] + off2, Bc + (2 * w + 1) * 512 + lane * 8);
    }
    SBAR();
    LGKM0();
    __builtin_amdgcn_s_setprio(1);
#pragma unroll
    for (int m = 0; m < 4; ++m)
#pragma unroll
      for (int n = 0; n < 4; ++n)
        acc[m + 4][n] = __builtin_amdgcn_mfma_f32_16x16x32_bf16(
            a1[m], b0[n], acc[m + 4][n], 0, 0, 0);
    __builtin_amdgcn_s_setprio(0);
    SBAR();

    // ---- phase 2: read A m4-7/kk1 + B kk1; stage A ksub0 (t+2)
#pragma unroll
    for (int m = 0; m < 4; ++m)
      a3[m] = *(const bf16x8*)&Ac[8192 + baseA + (m + 4) * 512];
#pragma unroll
    for (int n = 0; n < 4; ++n)
      b1[n] = *(const bf16x8*)&Bc[8192 + baseB + n * 512];
    if (stg) {
      GLOAD_LDS16(pA[0] + off2, Ac + (2 * w) * 512 + lane * 8);
      GLOAD_LDS16(pA[1] + off2, Ac + (2 * w + 1) * 512 + lane * 8);
    }
    SBAR();
    LGKM0();
    __builtin_amdgcn_s_setprio(1);
#pragma unroll
    for (int m = 0; m < 4; ++m)
#pragma unroll
      for (int n = 0; n < 4; ++n)
        acc[m][n] = __builtin_amdgcn_mfma_f32_16x16x32_bf16(a2[m], b1[n],
                                                            acc[m][n], 0, 0, 0);
    __builtin_amdgcn_s_setprio(0);
    SBAR();

    // ---- phase 3: stage A ksub1 + B ksub1 (t+2); boundary vmcnt; MFMA
    if (stg) {
      GLOAD_LDS16(pA[0] + off2 + 32, Ac + 8192 + (2 * w) * 512 + lane * 8);
      GLOAD_LDS16(pA[1] + off2 + 32, Ac + 8192 + (2 * w + 1) * 512 + lane * 8);
      GLOAD_LDS16(pB[0] + off2 + 32, Bc + 8192 + (2 * w) * 512 + lane * 8);
      GLOAD_LDS16(pB[1] + off2 + 32, Bc + 8192 + (2 * w + 1) * 512 + lane * 8);
    }
    if (t < NT - 1) {
      if (stg) {
        VMCNT(8);
      } else {
        VMCNT(0);
      }
    }
    SBAR();
    __builtin_amdgcn_s_setprio(1);
#pragma unroll
    for (int m = 0; m < 4; ++m)
#pragma unroll
      for (int n = 0; n < 4; ++n)
        acc[m + 4][n] = __builtin_amdgcn_mfma_f32_16x16x32_bf16(
            a3[m], b1[n], acc[m + 4][n], 0, 0, 0);
    __builtin_amdgcn_s_setprio(0);
    SBAR();
  }
}

// ---------------------------------------------------------------------------
// Fused QKV (R2 verbatim): grid 768 x 512thr, XCD-chunked.
// ---------------------------------------------------------------------------
__global__ __launch_bounds__(512, 2) void qkv_gemm8(
    const short* __restrict__ xb, const short* __restrict__ Wb,
    short* __restrict__ qkv) {
  __shared__ __align__(16) short As[32768];
  __shared__ __align__(16) short Bs[32768];
  int f = blockIdx.x;
  int s = (f & 7) * 96 + (f >> 3);  // XCD-chunked (768 % 8 == 0)
  int mt = s / 12, nt = s % 12;
  int z = nt >> 2, ntl = nt & 3;
  const short* gB = Wb + (size_t)z * AA * EE + (size_t)(ntl * 256) * EE;
  f32x4 acc[8][4];
#pragma unroll
  for (int m = 0; m < 8; ++m)
#pragma unroll
    for (int n = 0; n < 4; ++n) acc[m][n] = (f32x4){0.f, 0.f, 0.f, 0.f};
  gemm256_core(xb, EE, mt * 256, gB, EE, 0, EE / 64, As, Bs, acc);

  short* o = qkv + (size_t)z * MM * AA;
  int lane = threadIdx.x & 63, w = threadIdx.x >> 6, wr = w >> 2, wc = w & 3;
  int lrow = lane & 15, lk4 = (lane >> 4) * 4;
  int row0 = mt * 256 + wr * 128;
  int col0 = ntl * 256 + wc * 64;
#pragma unroll
  for (int m = 0; m < 8; ++m)
#pragma unroll
    for (int n = 0; n < 4; ++n)
#pragma unroll
      for (int r = 0; r < 4; ++r) {
        int row = row0 + m * 16 + lk4 + r;
        int col = col0 + n * 16 + lrow;
        __hip_bfloat16 h = __float2bfloat16(acc[m][n][r]);
        o[(size_t)row * AA + col] = *(short*)&h;
      }
}

// ---------------------------------------------------------------------------
// R1-style 128x128 helpers (score + pv bodies).
// ---------------------------------------------------------------------------
__device__ __forceinline__ void stage_tile(const short* __restrict__ g,
                                           size_t stride, short* lds, int tid) {
#pragma unroll
  for (int r = 0; r < 4; ++r) {
    int t = r * 256 + tid;
    int row = t >> 3;
    int c = (t & 7) * 8;
    GLOAD_LDS16(g + (size_t)row * stride + c, lds + (size_t)t * 8);
  }
}

__device__ __forceinline__ void mfma_step(const short* As, const short* Bs,
                                          f32x4 acc[4][4], int lane, int wr,
                                          int wc) {
  int lrow = lane & 15;
  int lk = (lane >> 4) * 8;
#pragma unroll
  for (int kk = 0; kk < 64; kk += 32) {
    bf16x8 a[4], b[4];
#pragma unroll
    for (int i = 0; i < 4; ++i)
      a[i] = *(const bf16x8*)&As[(wr * 64 + i * 16 + lrow) * 64 + kk + lk];
#pragma unroll
    for (int j = 0; j < 4; ++j)
      b[j] = *(const bf16x8*)&Bs[(wc * 64 + j * 16 + lrow) * 64 + kk + lk];
#pragma unroll
    for (int i = 0; i < 4; ++i)
#pragma unroll
      for (int j = 0; j < 4; ++j)
        acc[i][j] =
            __builtin_amdgcn_mfma_f32_16x16x32_bf16(a[i], b[j], acc[i][j], 0, 0, 0);
  }
}

__global__ void cvt_bf16(const float* __restrict__ src, short* __restrict__ dst,
                         int n4) {
  int stride = gridDim.x * blockDim.x;
  for (int i = blockIdx.x * blockDim.x + threadIdx.x; i < n4; i += stride) {
    float4 v = ((const float4*)src)[i];
    __hip_bfloat16 h0 = __float2bfloat16(v.x);
    __hip_bfloat16 h1 = __float2bfloat16(v.y);
    __hip_bfloat16 h2 = __float2bfloat16(v.z);
    __hip_bfloat16 h3 = __float2bfloat16(v.w);
    short4 o;
    o.x = *(short*)&h0;
    o.y = *(short*)&h1;
    o.z = *(short*)&h2;
    o.w = *(short*)&h3;
    ((short4*)dst)[i] = o;
  }
}

__global__ void cvt_w3(const float* __restrict__ wq, const float* __restrict__ wk,
                       const float* __restrict__ wv, short* __restrict__ dst) {
  const int n4 = AA * EE / 4;
  int stride = gridDim.x * blockDim.x;
  for (int i = blockIdx.x * blockDim.x + threadIdx.x; i < 3 * n4; i += stride) {
    const float* src = (i < n4) ? wq : (i < 2 * n4 ? wk : wv);
    int ii = (i < n4) ? i : (i < 2 * n4 ? i - n4 : i - 2 * n4);
    float4 v = ((const float4*)src)[ii];
    __hip_bfloat16 h0 = __float2bfloat16(v.x);
    __hip_bfloat16 h1 = __float2bfloat16(v.y);
    __hip_bfloat16 h2 = __float2bfloat16(v.z);
    __hip_bfloat16 h3 = __float2bfloat16(v.w);
    short4 o;
    o.x = *(short*)&h0;
    o.y = *(short*)&h1;
    o.z = *(short*)&h2;
    o.w = *(short*)&h3;
    ((short4*)dst)[i] = o;
  }
}

__global__ __launch_bounds__(256) void transpose_v(const short* __restrict__ Vb,
                                                   short* __restrict__ Vt) {
  __shared__ __align__(16) short lds[64 * 72];
  int t0 = blockIdx.x * 64;
  int d0 = blockIdx.y * 64;
  int b = blockIdx.z;
  int tid = threadIdx.x;
  const short* src = Vb + ((size_t)b * TT + t0) * AA + d0;
#pragma unroll
  for (int r = 0; r < 2; ++r) {
    int t = r * 256 + tid;
    int row = t >> 3;
    int c = (t & 7) * 8;
    *(bf16x8*)&lds[row * 72 + c] = *(const bf16x8*)&src[(size_t)row * AA + c];
  }
  __syncthreads();
  short* dst = Vt + ((size_t)b * AA + d0) * TT + t0;
#pragma unroll
  for (int r = 0; r < 2; ++r) {
    int t = r * 256 + tid;
    int d = t >> 3;
    int c = (t & 7) * 8;
    bf16x8 w;
#pragma unroll
    for (int e = 0; e < 8; ++e) w[e] = lds[(c + e) * 72 + d];
    *(bf16x8*)&dst[(size_t)d * TT + c] = w;
  }
}

// ---------------------------------------------------------------------------
// Scores (R4): compact lower-triangle grid 1088 (8 b x 136 tri), XCD = batch.
// ---------------------------------------------------------------------------
__global__ __launch_bounds__(256) void score_gemm(const short* __restrict__ Qb,
                                                  const short* __restrict__ Kb,
                                                  short* __restrict__ Pu,
                                                  float* __restrict__ lsum) {
  int f = blockIdx.x;
  int b = f & 7;
  int j = f >> 3;  // tri index in [0,136)
  int mt = 0;
  while ((mt + 1) * (mt + 2) / 2 <= j) ++mt;
  int nt = j - mt * (mt + 1) / 2;
  int q0 = mt * 128, c0 = nt * 128;

  __shared__ __align__(16) short As[128 * 64];
  __shared__ __align__(16) short Bs[128 * 64];
  int tid = threadIdx.x;
  int lane = tid & 63, wid = tid >> 6, wr = wid >> 1, wc = wid & 1;
  const short* Q = Qb + (size_t)b * TT * AA;
  const short* K = Kb + (size_t)b * TT * AA;
  f32x4 acc[4][4];
#pragma unroll
  for (int i = 0; i < 4; ++i)
#pragma unroll
    for (int jj = 0; jj < 4; ++jj) acc[i][jj] = (f32x4){0.f, 0.f, 0.f, 0.f};

  for (int k0 = 0; k0 < AA; k0 += 64) {
    stage_tile(Q + (size_t)q0 * AA + k0, AA, As, tid);
    stage_tile(K + (size_t)c0 * AA + k0, AA, Bs, tid);
    __syncthreads();
    mfma_step(As, Bs, acc, lane, wr, wc);
    __syncthreads();
  }
  const float scale = 0.03125f;  // 1/sqrt(1024)
  short* P = Pu + (size_t)b * TT * TT;
  int lrow = lane & 15, lk4 = (lane >> 4) * 4;
#pragma unroll
  for (int i = 0; i < 4; ++i) {
#pragma unroll
    for (int r = 0; r < 4; ++r) {
      int q = q0 + wr * 64 + i * 16 + lk4 + r;
      float rs = 0.f;
#pragma unroll
      for (int jj = 0; jj < 4; ++jj) {
        int kx = c0 + wc * 64 + jj * 16 + lrow;
        float e = (kx <= q) ? __expf(acc[i][jj][r] * scale) : 0.f;
        rs += e;
        __hip_bfloat16 h = __float2bfloat16(e);
        P[(size_t)q * TT + kx] = *(short*)&h;
      }
      rs += __shfl_xor(rs, 1);
      rs += __shfl_xor(rs, 2);
      rs += __shfl_xor(rs, 4);
      rs += __shfl_xor(rs, 8);
      if (lrow == 0) atomicAdd(&lsum[b * TT + q], rs);
    }
  }
}

// ---------------------------------------------------------------------------
// PV balanced: block handles q-strips mt=p and mt=15-p (17 K-subtiles total,
// uniform). grid 512 (8 b x 8 p x 8 nt) = 2 blocks/CU, XCD = batch.
// ---------------------------------------------------------------------------
__global__ __launch_bounds__(256) void pv_gemm(const short* __restrict__ Pu,
                                               const short* __restrict__ Vt,
                                               const float* __restrict__ lsum,
                                               float* __restrict__ out) {
  int f = blockIdx.x;
  int b = f & 7;
  int j = f >> 3;          // [0,64)
  int p = j >> 3;          // [0,8)
  int nt = j & 7;
  int n0 = nt * 128;

  __shared__ __align__(16) short As[128 * 64];
  __shared__ __align__(16) short Bs[128 * 64];
  int tid = threadIdx.x;
  int lane = tid & 63, wid = tid >> 6, wr = wid >> 1, wc = wid & 1;
  const short* P = Pu + (size_t)b * TT * TT;
  const short* V = Vt + (size_t)b * AA * TT;
  int lrow = lane & 15, lk4 = (lane >> 4) * 4;

#pragma unroll
  for (int s = 0; s < 2; ++s) {
    int mt = s ? (15 - p) : p;
    int q0 = mt * 128;
    f32x4 acc[4][4];
#pragma unroll
    for (int i = 0; i < 4; ++i)
#pragma unroll
      for (int jj = 0; jj < 4; ++jj) acc[i][jj] = (f32x4){0.f, 0.f, 0.f, 0.f};

    int kend = q0 + 128;
    for (int k0 = 0; k0 < kend; k0 += 64) {
      stage_tile(P + (size_t)q0 * TT + k0, TT, As, tid);
      stage_tile(V + (size_t)n0 * TT + k0, TT, Bs, tid);
      __syncthreads();
      mfma_step(As, Bs, acc, lane, wr, wc);
      __syncthreads();
    }
#pragma unroll
    for (int i = 0; i < 4; ++i) {
#pragma unroll
      for (int r = 0; r < 4; ++r) {
        int q = q0 + wr * 64 + i * 16 + lk4 + r;
        float linv = 1.0f / lsum[b * TT + q];
#pragma unroll
        for (int jj = 0; jj < 4; ++jj) {
          int d = n0 + wc * 64 + jj * 16 + lrow;
          out[((size_t)(b * TT + q)) * AA + d] = acc[i][jj][r] * linv;
        }
      }
    }
  }
}

extern "C" void kernel_launch(void* const* d_in, const int* in_sizes, int n_in,
                              void* d_out, int out_size, void* d_ws,
                              size_t ws_size, hipStream_t stream) {
  const float* x = (const float*)d_in[0];
  const float* Wq = (const float*)d_in[1];
  const float* Wk = (const float*)d_in[2];
  const float* Wv = (const float*)d_in[3];

  char* ws = (char*)d_ws;
  size_t oWb = 0;
  size_t oQb = oWb + (size_t)3 * AA * EE * 2;   // 6 MB weights
  size_t oKb = oQb + (size_t)MM * AA * 2;
  size_t oVb = oKb + (size_t)MM * AA * 2;
  size_t oVt = oVb + (size_t)MM * AA * 2;
  size_t oLs = oVt + (size_t)MM * AA * 2;
  size_t oXb = oLs + (size_t)MM * 4;
  size_t oPu = oXb;  // Pu (67MB) overlaps Xb (33MB): Xb dead after qkv

  short* Wb = (short*)(ws + oWb);
  short* Qb = (short*)(ws + oQb);
  short* Kb = (short*)(ws + oKb);
  short* Vb = (short*)(ws + oVb);
  short* Vt = (short*)(ws + oVt);
  float* Ls = (float*)(ws + oLs);
  short* Xb = (short*)(ws + oXb);
  short* Pu = (short*)(ws + oPu);

  cvt_bf16<<<2048, 256, 0, stream>>>(x, Xb, MM * EE / 4);
  cvt_w3<<<768, 256, 0, stream>>>(Wq, Wk, Wv, Wb);
  hipMemsetAsync(Ls, 0, (size_t)MM * 4, stream);

  qkv_gemm8<<<768, 512, 0, stream>>>(Xb, Wb, Qb);
  transpose_v<<<dim3(32, 16, 8), 256, 0, stream>>>(Vb, Vt);
  score_gemm<<<1088, 256, 0, stream>>>(Qb, Kb, Pu, Ls);
  pv_gemm<<<512, 256, 0, stream>>>(Pu, Vt, Ls, (float*)d_out);
}